// Round 1
// 549.867 us; speedup vs baseline: 1.1151x; 1.1151x over previous
//
#include <hip/hip_runtime.h>

// STFT: N_FFT=1024, HOP=256, WIN=1024, SIG_LEN=2^24, pad=768 each side.
// n_frames=65539 computed frames, n_rows=65542 output rows, half_n=513.
// Circular shift by 512 (zero-phase) == multiply spectrum by (-1)^k.
//
// FP64 FFT PIPELINE, FP32 TRANSCENDENTALS: phase branch-cut (atan2 at +/-pi)
// decisions must match the reference's sign of Yi even at bins where
// |Yi| ~ 1e-7 (deep spectral nulls). fp32 FFT error (~1e-6) flips those
// signs -> 2*pi phase errors (earlier rounds: absmax 6.28). fp64 FFT error
// ~1e-15 rel sits far below the min |Yi| ~ 4e-8. HOWEVER the final
// sqrt/atan2 do NOT need fp64: casting fp64 Yr/Yi -> fp32 preserves the
// sign exactly (incl. +/-0), and atan2f/sqrtf add only ~1e-6 error --
// far below the 0.0156 absmax already present (reference's own fp32 FFT
// at nulls). This removes the fp64 divide + poly chains (~half the VALU).

#define SIG_LEN   16777216
#define N_FRAMES  65539
#define N_ROWS    65542
#define HALF_N    513
#define FRAMES_FLOATS (N_FRAMES * HALF_N)   // 33621507
#define MAG_SZ        (N_ROWS   * HALF_N)   // 33623046

// d_ws layout (doubles):
//   [0, 1024)        window (hamming/32)
//   [1024, 1536)     tw: 256 x double2, e^{-2*pi*i*p/512}
//   [1536, 2562)     rtw: 513 x double2, e^{-2*pi*i*k/1024}

__global__ void init_tables(double* __restrict__ ws) {
  int i = blockIdx.x * 256 + threadIdx.x;
  const double PI = 3.14159265358979323846;
  if (i < 1024) {
    ws[i] = (0.54 - 0.46 * cos(2.0 * PI * (double)i / 1023.0)) / 32.0;
  }
  if (i < 256) {
    double a = -2.0 * PI * (double)i / 512.0;
    ws[1024 + 2 * i]     = cos(a);
    ws[1024 + 2 * i + 1] = sin(a);
  }
  if (i < 513) {
    double a = -2.0 * PI * (double)i / 1024.0;
    ws[1536 + 2 * i]     = cos(a);
    ws[1536 + 2 * i + 1] = sin(a);
  }
}

// rows n_frames..n_rows-1 stay zero in the reference; d_out is poisoned, so write them.
__global__ void zero_tail(float* __restrict__ out) {
  int i = blockIdx.x * 256 + threadIdx.x;
  if (i < (MAG_SZ - FRAMES_FLOATS)) {   // 1539 per output
    out[FRAMES_FLOATS + i] = 0.0f;
    out[MAG_SZ + FRAMES_FLOATS + i] = 0.0f;
  }
}

__global__ __launch_bounds__(256) void stft_frame(const float* __restrict__ x,
                                                  const double* __restrict__ ws,
                                                  float* __restrict__ out) {
  __shared__ double2 z[512];     // FFT working buffer          8 KB
  __shared__ double2 twl[256];   // 512-point FFT twiddles      4 KB

  const int f = blockIdx.x;
  const int t = threadIdx.x;

  twl[t] = ((const double2*)(ws + 1024))[t];

  // Load + window + half-size pack + bit-reverse, directly from global.
  // z[rev9(m)] = x[2m]*win[2m] + i*x[2m+1]*win[2m+1].
  // Padded signal index = f*HOP + j, x index = that - 768.
  const int base = f * 256 - 768;
#pragma unroll
  for (int mm = 0; mm < 2; ++mm) {
    int m = t + mm * 256;
    int idx0 = base + 2 * m;          // even -> float2-aligned
    double v0, v1;
    if (idx0 >= 0 && idx0 + 1 < SIG_LEN) {
      float2 xv = *(const float2*)(x + idx0);
      v0 = (double)xv.x;
      v1 = (double)xv.y;
    } else {
      int i1 = idx0 + 1;
      v0 = (idx0 >= 0 && idx0 < SIG_LEN) ? (double)x[idx0] : 0.0;
      v1 = (i1 >= 0 && i1 < SIG_LEN) ? (double)x[i1] : 0.0;
    }
    double2 wv = *(const double2*)(ws + 2 * m);   // win[2m], win[2m+1]
    int r = (int)(__brev((unsigned)m) >> 23);     // 9-bit reverse
    z[r] = make_double2(v0 * wv.x, v1 * wv.y);
  }
  __syncthreads();

  // 512-point complex FFT, radix-2 DIT, 9 stages, 256 butterflies/stage.
  // Stage 1: twiddle is exactly (1,0) -> pure add/sub (bit-identical to
  // the multiplied form since cos(0)=1.0, sin(0)=0.0 exactly).
  {
    int i0 = 2 * t;
    double2 a = z[i0];
    double2 b = z[i0 + 1];
    z[i0]     = make_double2(a.x + b.x, a.y + b.y);
    z[i0 + 1] = make_double2(a.x - b.x, a.y - b.y);
  }
  __syncthreads();

#pragma unroll
  for (int s = 2; s <= 9; ++s) {
    int half = 1 << (s - 1);
    int p = t & (half - 1);
    int g = t >> (s - 1);
    int i0 = (g << s) | p;
    int i1 = i0 + half;
    double2 w = twl[p << (9 - s)];
    double2 a = z[i0];
    double2 b = z[i1];
    double tr = w.x * b.x - w.y * b.y;
    double ti = w.x * b.y + w.y * b.x;
    z[i0] = make_double2(a.x + tr, a.y + ti);
    z[i1] = make_double2(a.x - tr, a.y - ti);
    __syncthreads();
  }

  // Untwiddle to rfft bins k=0..512 (fp64), then mag/phase in fp32.
  const double2* rtw = (const double2*)(ws + 1536);
  for (int k = t; k < HALF_N; k += 256) {
    double2 Zk = z[k & 511];
    double2 Zm = z[(512 - k) & 511];
    // E = (Zk + conj(Zm))/2 ; O = (Zk - conj(Zm))/(2i) ; Y = E + w*O
    double Er = 0.5 * (Zk.x + Zm.x);
    double Ei = 0.5 * (Zk.y - Zm.y);
    double Or = 0.5 * (Zk.y + Zm.y);
    double Oi = -0.5 * (Zk.x - Zm.x);
    double2 w = rtw[k];
    double Yr = Er + w.x * Or - w.y * Oi;
    double Yi = Ei + w.x * Oi + w.y * Or;
    if ((k & 511) == 0) Yi = 0.0;    // k==0 / k==512: exactly-real bins, imag = +0
    // fp64 -> fp32 cast preserves sign(Yi) exactly; fp32 transcendentals
    // add ~1e-6 error, far below the 0.0156 tolerance band.
    float yr = (float)Yr;
    float yi = (float)Yi;
    float mag = sqrtf(yr * yr + yi * yi);
    float pr = (k & 1) ? -yr : yr;   // (-1)^k from the zero-phase circular shift
    float pi = (k & 1) ? -yi : yi;
    float ph = atan2f(pi, pr);
    out[f * HALF_N + k] = mag;
    out[MAG_SZ + f * HALF_N + k] = ph;
  }
}

extern "C" void kernel_launch(void* const* d_in, const int* in_sizes, int n_in,
                              void* d_out, int out_size, void* d_ws, size_t ws_size,
                              hipStream_t stream) {
  const float* x = (const float*)d_in[0];
  float* out = (float*)d_out;
  double* ws = (double*)d_ws;

  hipLaunchKernelGGL(init_tables, dim3(4), dim3(256), 0, stream, ws);
  hipLaunchKernelGGL(zero_tail, dim3(7), dim3(256), 0, stream, out);
  hipLaunchKernelGGL(stft_frame, dim3(N_FRAMES), dim3(256), 0, stream, x, ws, out);
}

// Round 2
// 441.534 us; speedup vs baseline: 1.3887x; 1.2454x over previous
//
#include <hip/hip_runtime.h>

// STFT: N_FFT=1024, HOP=256, WIN=1024, SIG_LEN=2^24, pad=768 each side.
// n_frames=65539 computed frames, n_rows=65542 output rows, half_n=513.
// Circular shift by 512 (zero-phase) == multiply spectrum by (-1)^k.
//
// FP64 FFT, FP32 TRANSCENDENTALS (see round-1 notes): sign(Yi) at deep
// spectral nulls must match the fp64 reference -> FFT in fp64; final
// sqrt/atan2 in fp32 after casting (sign-preserving).
//
// ROUND-2 RESTRUCTURE: radix-8 (512 = 8^3), ONE WAVE PER FRAME.
//  - 3 register-resident 8-point DFT stages (8 complex fp64 per lane),
//    only 2 LDS transpose exchanges + 1 natural-order store, vs 9 LDS
//    round-trips for radix-2. LDS pipe was ~90% busy (8.9e7 conflict
//    cycles + base traffic) -> ~5x less LDS traffic.
//  - pad(e) = e + (e>>3) + (e>>6): every exchange pattern lands <=2-way
//    on banks (2-way is free on CDNA4).
//  - NO __syncthreads: waves independent, wave-synchronous LDS via
//    s_waitcnt lgkmcnt(0) (DS ops are in-order per wave).
//  - twiddles: per-lane power chains from the W512 table (6 cmuls),
//    error ~1e-15, far below the ~4e-8 null floor.

#define SIG_LEN   16777216
#define N_FRAMES  65539
#define N_ROWS    65542
#define HALF_N    513
#define FRAMES_FLOATS (N_FRAMES * HALF_N)   // 33621507
#define MAG_SZ        (N_ROWS   * HALF_N)   // 33623046

// d_ws layout (doubles):
//   [0, 1024)        window (hamming/32)
//   [1024, 1536)     tw: 256 x double2, W512^p = e^{-2*pi*i*p/512}, p=0..255
//   [1536, 2562)     rtw: 513 x double2, e^{-2*pi*i*k/1024}

__global__ void init_tables(double* __restrict__ ws) {
  int i = blockIdx.x * 256 + threadIdx.x;
  const double PI = 3.14159265358979323846;
  if (i < 1024) {
    ws[i] = (0.54 - 0.46 * cos(2.0 * PI * (double)i / 1023.0)) / 32.0;
  }
  if (i < 256) {
    double a = -2.0 * PI * (double)i / 512.0;
    ws[1024 + 2 * i]     = cos(a);
    ws[1024 + 2 * i + 1] = sin(a);
  }
  if (i < 513) {
    double a = -2.0 * PI * (double)i / 1024.0;
    ws[1536 + 2 * i]     = cos(a);
    ws[1536 + 2 * i + 1] = sin(a);
  }
}

// rows n_frames..n_rows-1 stay zero in the reference; d_out is poisoned, so write them.
__global__ void zero_tail(float* __restrict__ out) {
  int i = blockIdx.x * 256 + threadIdx.x;
  if (i < (MAG_SZ - FRAMES_FLOATS)) {   // 1539 per output
    out[FRAMES_FLOATS + i] = 0.0f;
    out[MAG_SZ + FRAMES_FLOATS + i] = 0.0f;
  }
}

// LDS pad: <=2-way bank aliasing for all exchange patterns used below.
#define PAD(e) ((e) + ((e) >> 3) + ((e) >> 6))

#define CMUL(vr, vi, wx, wy) { double _t = (vr)*(wx) - (vi)*(wy); \
                               (vi) = (vr)*(wy) + (vi)*(wx); (vr) = _t; }

// In-place 8-point DFT, natural order in and out. y[k] = sum_n a[n] W8^{nk}.
__device__ __forceinline__ void dft8(double* ar, double* ai) {
  const double S = 0.70710678118654752440;  // sqrt(2)/2
  double s0r = ar[0] + ar[4], s0i = ai[0] + ai[4];
  double s1r = ar[0] - ar[4], s1i = ai[0] - ai[4];
  double s2r = ar[2] + ar[6], s2i = ai[2] + ai[6];
  double s3r = ar[2] - ar[6], s3i = ai[2] - ai[6];
  double t0r = ar[1] + ar[5], t0i = ai[1] + ai[5];
  double t1r = ar[1] - ar[5], t1i = ai[1] - ai[5];
  double t2r = ar[3] + ar[7], t2i = ai[3] + ai[7];
  double t3r = ar[3] - ar[7], t3i = ai[3] - ai[7];

  double e0r = s0r + s2r, e0i = s0i + s2i;
  double e2r = s0r - s2r, e2i = s0i - s2i;
  double e1r = s1r + s3i, e1i = s1i - s3r;   // s1 - i*s3
  double e3r = s1r - s3i, e3i = s1i + s3r;   // s1 + i*s3
  double o0r = t0r + t2r, o0i = t0i + t2i;
  double o2r = t0r - t2r, o2i = t0i - t2i;
  double o1r = t1r + t3i, o1i = t1i - t3r;
  double o3r = t1r - t3i, o3i = t1i + t3r;

  double u1r = S * (o1r + o1i), u1i = S * (o1i - o1r);   // W8^1 * o1
  double u2r = o2i,             u2i = -o2r;              // -i   * o2
  double u3r = S * (o3i - o3r), u3i = -S * (o3r + o3i);  // W8^3 * o3

  ar[0] = e0r + o0r; ai[0] = e0i + o0i;
  ar[4] = e0r - o0r; ai[4] = e0i - o0i;
  ar[1] = e1r + u1r; ai[1] = e1i + u1i;
  ar[5] = e1r - u1r; ai[5] = e1i - u1i;
  ar[2] = e2r + u2r; ai[2] = e2i + u2i;
  ar[6] = e2r - u2r; ai[6] = e2i - u2i;
  ar[3] = e3r + u3r; ai[3] = e3i + u3i;
  ar[7] = e3r - u3r; ai[7] = e3i - u3i;
}

// reg r *= w^r, r=1..7 (power chain, ~1e-15 error)
__device__ __forceinline__ void twmul(double* ar, double* ai, double wx, double wy) {
  double px = wx, py = wy;
  CMUL(ar[1], ai[1], px, py);
#pragma unroll
  for (int r = 2; r < 8; ++r) {
    double nx = px * wx - py * wy;
    double ny = px * wy + py * wx;
    px = nx; py = ny;
    CMUL(ar[r], ai[r], px, py);
  }
}

__global__ __launch_bounds__(256) void stft_frame(const float* __restrict__ x,
                                                  const double* __restrict__ ws,
                                                  float* __restrict__ out) {
  __shared__ double2 zbuf[4][584];   // PAD(511)=581; 584 for alignment. 37.4 KB

  const int wv = threadIdx.x >> 6;   // wave id = which frame in this block
  const int l  = threadIdx.x & 63;   // lane
  const int f  = blockIdx.x * 4 + wv;
  if (f >= N_FRAMES) return;         // safe: no barriers anywhere below
  double2* z = zbuf[wv];

  // ---- load + window + half-size pack: reg[n2] = z_in[64*n2 + l] ----
  // z_in[m] = yw[2m] + i*yw[2m+1], yw[j] = x[base+j]*win[j]
  double ar[8], ai[8];
  const int base = f * 256 - 768;
#pragma unroll
  for (int n2 = 0; n2 < 8; ++n2) {
    int j  = 128 * n2 + 2 * l;       // even yw index; base+j is even -> float2 ok
    int ix = base + j;
    double v0, v1;
    if (ix >= 0 && ix + 1 < SIG_LEN) {
      float2 xv = *(const float2*)(x + ix);
      v0 = (double)xv.x; v1 = (double)xv.y;
    } else {
      v0 = (ix >= 0 && ix < SIG_LEN) ? (double)x[ix] : 0.0;
      v1 = (ix + 1 >= 0 && ix + 1 < SIG_LEN) ? (double)x[ix + 1] : 0.0;
    }
    double2 wn = *(const double2*)(ws + j);   // win[j], win[j+1]
    ar[n2] = v0 * wn.x;
    ai[n2] = v1 * wn.y;
  }

  const int g = l >> 3;   // high digit of lane (k0 after stage 1)
  const int q = l & 7;    // low digit of lane

  // ---- stage 1: DFT over n2 (reg axis) -> k0; twiddle W512^{l*k0} ----
  dft8(ar, ai);
  {
    double2 w = ((const double2*)(ws + 1024))[l];      // W512^l
    twmul(ar, ai, w.x, w.y);
  }

  // ---- exchange A: [k0*64 + n1*8 + n0] ; write reg k0 @ 64r+l (contig),
  //      read reg n1 @ 64g + 8r + q ----
#pragma unroll
  for (int r = 0; r < 8; ++r) {
    int e = 64 * r + l;
    z[PAD(e)] = make_double2(ar[r], ai[r]);
  }
  asm volatile("s_waitcnt lgkmcnt(0)" ::: "memory");
#pragma unroll
  for (int r = 0; r < 8; ++r) {
    int e = 64 * g + 8 * r + q;
    double2 v = z[PAD(e)];
    ar[r] = v.x; ai[r] = v.y;
  }

  // ---- stage 2: DFT over n1 -> k1; twiddle W64^{n0*k1}, n0=q ----
  dft8(ar, ai);
  {
    double2 w = ((const double2*)(ws + 1024))[8 * q];  // W512^{8q} = W64^q
    twmul(ar, ai, w.x, w.y);
  }

  // ---- exchange B: write reg k1 @ 64g + 8r + q, read reg n0 @ 64g + 8q + r ----
  // (DS ops are in-order per wave: writes cannot pass the prior reads)
#pragma unroll
  for (int r = 0; r < 8; ++r) {
    int e = 64 * g + 8 * r + q;
    z[PAD(e)] = make_double2(ar[r], ai[r]);
  }
  asm volatile("s_waitcnt lgkmcnt(0)" ::: "memory");
#pragma unroll
  for (int r = 0; r < 8; ++r) {
    int e = 64 * g + 8 * q + r;      // contiguous 8 elements per lane
    double2 v = z[PAD(e)];
    ar[r] = v.x; ai[r] = v.y;
  }

  // ---- stage 3: DFT over n0 -> k2 (no twiddle) ----
  dft8(ar, ai);

  // ---- natural-order store: reg k2 holds X[k], k = g + 8q + 64*k2 ----
#pragma unroll
  for (int r = 0; r < 8; ++r) {
    int e = 64 * r + 8 * q + g;
    z[PAD(e)] = make_double2(ar[r], ai[r]);
  }
  asm volatile("s_waitcnt lgkmcnt(0)" ::: "memory");

  // ---- untwiddle to rfft bins k=0..512 (fp64), mag/phase in fp32 ----
  const double2* rtw = (const double2*)(ws + 1536);
  for (int k = l; k < HALF_N; k += 64) {
    double2 Zk = z[PAD(k & 511)];
    double2 Zm = z[PAD((512 - k) & 511)];
    // E = (Zk + conj(Zm))/2 ; O = (Zk - conj(Zm))/(2i) ; Y = E + w*O
    double Er = 0.5 * (Zk.x + Zm.x);
    double Ei = 0.5 * (Zk.y - Zm.y);
    double Or = 0.5 * (Zk.y + Zm.y);
    double Oi = -0.5 * (Zk.x - Zm.x);
    double2 w = rtw[k];
    double Yr = Er + w.x * Or - w.y * Oi;
    double Yi = Ei + w.x * Oi + w.y * Or;
    if ((k & 511) == 0) Yi = 0.0;    // k==0 / k==512: exactly-real bins, imag = +0
    float yr = (float)Yr;
    float yi = (float)Yi;
    float mag = sqrtf(yr * yr + yi * yi);
    float pr = (k & 1) ? -yr : yr;   // (-1)^k from the zero-phase circular shift
    float pi = (k & 1) ? -yi : yi;
    float ph = atan2f(pi, pr);
    out[f * HALF_N + k] = mag;
    out[MAG_SZ + f * HALF_N + k] = ph;
  }
}

extern "C" void kernel_launch(void* const* d_in, const int* in_sizes, int n_in,
                              void* d_out, int out_size, void* d_ws, size_t ws_size,
                              hipStream_t stream) {
  const float* x = (const float*)d_in[0];
  float* out = (float*)d_out;
  double* ws = (double*)d_ws;

  hipLaunchKernelGGL(init_tables, dim3(4), dim3(256), 0, stream, ws);
  hipLaunchKernelGGL(zero_tail, dim3(7), dim3(256), 0, stream, out);
  hipLaunchKernelGGL(stft_frame, dim3((N_FRAMES + 3) / 4), dim3(256), 0, stream,
                     x, ws, out);
}

// Round 3
// 403.546 us; speedup vs baseline: 1.5194x; 1.0941x over previous
//
#include <hip/hip_runtime.h>

// STFT: N_FFT=1024, HOP=256, WIN=1024, SIG_LEN=2^24, pad=768 each side.
// n_frames=65539 computed frames, n_rows=65542 output rows, half_n=513.
// Circular shift by 512 (zero-phase) == multiply spectrum by (-1)^k.
//
// FP64 FFT, FP32 TRANSCENDENTALS: sign(Yi) at deep spectral nulls must
// match the fp64 reference -> FFT + untwiddle in fp64; final sqrt/atan2
// in fp32 after casting (sign-preserving).
//
// ROUND-3: occupancy + VALU-trim on the radix-8 one-wave-per-frame design.
//  - XOR swizzle idx = 64*hi + 8*mid + (lo^mid) replaces additive PAD:
//    LDS/frame = exactly 8 KB -> 32 KB/block -> 5 blocks/CU (was 4).
//    All exchange patterns stay <=2-way per quarter-wave.
//  - Stage twiddles from precomputed tables (tw1[64][7], tw2[8][7]) --
//    kills the per-lane power chains (-48 fp64 insts/lane).
//  - Untwiddle via A/B tables: Y = Zk*A + conj(Zm)*B, A=0.5(1-i*w),
//    B=0.5(1+i*w) -- 8 fp64 ops/bin vs 14.
//  - k=512 handled as a tiny lane-0 special case (Y real = z0.x - z0.y),
//    not a 9th masked full-cost iteration.
//  - Wave-uniform bounds fast path (only frames 0..2 and 65536.. clamp).

#define SIG_LEN   16777216
#define N_FRAMES  65539
#define N_ROWS    65542
#define HALF_N    513
#define FRAMES_FLOATS (N_FRAMES * HALF_N)   // 33621507
#define MAG_SZ        (N_ROWS   * HALF_N)   // 33623046

// d_ws layout (doubles):
//   [0, 1024)        window (hamming/32), fp64
//   [1024, 1920)     tw1: 448 x double2, tw1[l*7+r-1] = e^{-2*pi*i*l*r/512}
//   [1920, 2032)     tw2: 56 x double2,  tw2[q*7+r-1] = e^{-2*pi*i*8*q*r/512}
//   [2048, 4100)     AB: 513 x {A.x,A.y,B.x,B.y}, w=e^{-i*pi*k/512},
//                    A=0.5(1-i*w), B=0.5(1+i*w)

__global__ void init_tables(double* __restrict__ ws) {
  int i = blockIdx.x * 256 + threadIdx.x;
  const double PI = 3.14159265358979323846;
  if (i < 1024) {
    ws[i] = (0.54 - 0.46 * cos(2.0 * PI * (double)i / 1023.0)) / 32.0;
  }
  if (i < 448) {
    int l = i / 7, r = i % 7 + 1;
    double a = -2.0 * PI * (double)(l * r) / 512.0;
    ws[1024 + 2 * i]     = cos(a);
    ws[1024 + 2 * i + 1] = sin(a);
  }
  if (i < 56) {
    int q = i / 7, r = i % 7 + 1;
    double a = -2.0 * PI * (double)(8 * q * r) / 512.0;
    ws[1920 + 2 * i]     = cos(a);
    ws[1920 + 2 * i + 1] = sin(a);
  }
  if (i < 513) {
    double th = PI * (double)i / 512.0;
    double c = cos(th), s = sin(th);
    ws[2048 + 4 * i]     = 0.5 * (1.0 - s);   // A.x
    ws[2048 + 4 * i + 1] = -0.5 * c;          // A.y
    ws[2048 + 4 * i + 2] = 0.5 * (1.0 + s);   // B.x
    ws[2048 + 4 * i + 3] = 0.5 * c;           // B.y
  }
}

// rows n_frames..n_rows-1 stay zero in the reference; d_out is poisoned, so write them.
__global__ void zero_tail(float* __restrict__ out) {
  int i = blockIdx.x * 256 + threadIdx.x;
  if (i < (MAG_SZ - FRAMES_FLOATS)) {   // 1539 per output
    out[FRAMES_FLOATS + i] = 0.0f;
    out[MAG_SZ + FRAMES_FLOATS + i] = 0.0f;
  }
}

#define CMUL(vr, vi, wx, wy) { double _t = (vr)*(wx) - (vi)*(wy); \
                               (vi) = (vr)*(wy) + (vi)*(wx); (vr) = _t; }

// In-place 8-point DFT, natural order in and out. y[k] = sum_n a[n] W8^{nk}.
__device__ __forceinline__ void dft8(double* ar, double* ai) {
  const double S = 0.70710678118654752440;  // sqrt(2)/2
  double s0r = ar[0] + ar[4], s0i = ai[0] + ai[4];
  double s1r = ar[0] - ar[4], s1i = ai[0] - ai[4];
  double s2r = ar[2] + ar[6], s2i = ai[2] + ai[6];
  double s3r = ar[2] - ar[6], s3i = ai[2] - ai[6];
  double t0r = ar[1] + ar[5], t0i = ai[1] + ai[5];
  double t1r = ar[1] - ar[5], t1i = ai[1] - ai[5];
  double t2r = ar[3] + ar[7], t2i = ai[3] + ai[7];
  double t3r = ar[3] - ar[7], t3i = ai[3] - ai[7];

  double e0r = s0r + s2r, e0i = s0i + s2i;
  double e2r = s0r - s2r, e2i = s0i - s2i;
  double e1r = s1r + s3i, e1i = s1i - s3r;   // s1 - i*s3
  double e3r = s1r - s3i, e3i = s1i + s3r;   // s1 + i*s3
  double o0r = t0r + t2r, o0i = t0i + t2i;
  double o2r = t0r - t2r, o2i = t0i - t2i;
  double o1r = t1r + t3i, o1i = t1i - t3r;
  double o3r = t1r - t3i, o3i = t1i + t3r;

  double u1r = S * (o1r + o1i), u1i = S * (o1i - o1r);   // W8^1 * o1
  double u2r = o2i,             u2i = -o2r;              // -i   * o2
  double u3r = S * (o3i - o3r), u3i = -S * (o3r + o3i);  // W8^3 * o3

  ar[0] = e0r + o0r; ai[0] = e0i + o0i;
  ar[4] = e0r - o0r; ai[4] = e0i - o0i;
  ar[1] = e1r + u1r; ai[1] = e1i + u1i;
  ar[5] = e1r - u1r; ai[5] = e1i - u1i;
  ar[2] = e2r + u2r; ai[2] = e2i + u2i;
  ar[6] = e2r - u2r; ai[6] = e2i - u2i;
  ar[3] = e3r + u3r; ai[3] = e3i + u3i;
  ar[7] = e3r - u3r; ai[7] = e3i - u3i;
}

__global__ __launch_bounds__(256, 5) void stft_frame(const float* __restrict__ x,
                                                     const double* __restrict__ ws,
                                                     float* __restrict__ out) {
  __shared__ double2 zbuf[4][512];   // exactly 32 KB -> 5 blocks/CU

  const int wv = threadIdx.x >> 6;   // wave id = which frame in this block
  const int l  = threadIdx.x & 63;   // lane
  const int f  = blockIdx.x * 4 + wv;
  if (f >= N_FRAMES) return;         // safe: no barriers anywhere below
  double2* z = zbuf[wv];

  const int g = l >> 3;   // high octal digit of lane
  const int q = l & 7;    // low octal digit of lane

  // ---- load + window + half-size pack: reg[n2] = z_in[64*n2 + l] ----
  // z_in[m] = yw[2m] + i*yw[2m+1], yw[j] = x[base+j]*win[j]
  double ar[8], ai[8];
  const int base = f * 256 - 768;
  if (base >= 0 && base + 1024 <= SIG_LEN) {
    // fast path: 65533 of 65539 frames
#pragma unroll
    for (int n2 = 0; n2 < 8; ++n2) {
      int j = 128 * n2 + 2 * l;
      float2 xv = *(const float2*)(x + base + j);
      double2 wn = *(const double2*)(ws + j);
      ar[n2] = (double)xv.x * wn.x;
      ai[n2] = (double)xv.y * wn.y;
    }
  } else {
#pragma unroll
    for (int n2 = 0; n2 < 8; ++n2) {
      int j  = 128 * n2 + 2 * l;
      int ix = base + j;
      double v0 = (ix >= 0 && ix < SIG_LEN) ? (double)x[ix] : 0.0;
      double v1 = (ix + 1 >= 0 && ix + 1 < SIG_LEN) ? (double)x[ix + 1] : 0.0;
      double2 wn = *(const double2*)(ws + j);
      ar[n2] = v0 * wn.x;
      ai[n2] = v1 * wn.y;
    }
  }

  // ---- stage 1: DFT over n2 (reg axis) -> k0; twiddle W512^{l*k0} ----
  dft8(ar, ai);
  {
    const double2* tw1 = (const double2*)(ws + 1024) + l * 7;
#pragma unroll
    for (int r = 1; r < 8; ++r) {
      double2 w = tw1[r - 1];
      CMUL(ar[r], ai[r], w.x, w.y);
    }
  }

  // ---- exchange A: idx_A(k0,n1,n0) = 64*k0 + 8*n1 + (n0^n1) ----
  // write: lane (n1=g, n0=q), op k0=r.  read: lane (k0=g, n0=q), op n1=r.
#pragma unroll
  for (int r = 0; r < 8; ++r) {
    z[64 * r + 8 * g + (q ^ g)] = make_double2(ar[r], ai[r]);
  }
  asm volatile("s_waitcnt lgkmcnt(0)" ::: "memory");
#pragma unroll
  for (int r = 0; r < 8; ++r) {
    double2 v = z[64 * g + 8 * r + (q ^ r)];
    ar[r] = v.x; ai[r] = v.y;
  }

  // ---- stage 2: DFT over n1 -> k1; twiddle W64^{n0*k1}, n0=q ----
  dft8(ar, ai);
  {
    const double2* tw2 = (const double2*)(ws + 1920) + q * 7;
#pragma unroll
    for (int r = 1; r < 8; ++r) {
      double2 w = tw2[r - 1];
      CMUL(ar[r], ai[r], w.x, w.y);
    }
  }

  // ---- exchange B: idx_B(k0,k1,n0) = 64*k0 + 8*k1 + (n0^k1) ----
  // write: lane (k0=g, n0=q), op k1=r.  read: lane (k0=g, k1=q), op n0=r.
  // (DS ops are in-order per wave: writes cannot pass the prior reads)
#pragma unroll
  for (int r = 0; r < 8; ++r) {
    z[64 * g + 8 * r + (q ^ r)] = make_double2(ar[r], ai[r]);
  }
  asm volatile("s_waitcnt lgkmcnt(0)" ::: "memory");
#pragma unroll
  for (int r = 0; r < 8; ++r) {
    double2 v = z[64 * g + 8 * q + (r ^ q)];
    ar[r] = v.x; ai[r] = v.y;
  }

  // ---- stage 3: DFT over n0 -> k2 (no twiddle) ----
  dft8(ar, ai);

  // ---- store: reg k2 holds X[k], k = 64*k2 + 8*q + g ----
  // idx_C(k) = (k & ~7) | ((k ^ (k>>3)) & 7)  -> here 64*r + 8*q + (g^q)
#pragma unroll
  for (int r = 0; r < 8; ++r) {
    z[64 * r + 8 * q + (g ^ q)] = make_double2(ar[r], ai[r]);
  }
  asm volatile("s_waitcnt lgkmcnt(0)" ::: "memory");

  // ---- untwiddle to rfft bins (fp64), mag/phase in fp32 ----
  // Y_k = Zk*A_k + conj(Zm)*B_k, Zm = Z[(512-k)&511]
  const double* AB = ws + 2048;
  const int czk = 8 * (l >> 3) + ((l & 7) ^ (l >> 3));   // idx_C(k) - 64*i
  const float sgn = (l & 1) ? -1.0f : 1.0f;              // (-1)^k, k=l+64i
#pragma unroll
  for (int i = 0; i < 8; ++i) {
    int k = l + 64 * i;
    double2 Zk = z[64 * i + czk];
    int km = (512 - k) & 511;
    double2 Zm = z[(km & ~7) | ((km ^ (km >> 3)) & 7)];
    const double* ab = AB + 4 * k;
    double Axv = ab[0], Ayv = ab[1], Bxv = ab[2], Byv = ab[3];
    double Yr = Zk.x * Axv - Zk.y * Ayv + Zm.x * Bxv + Zm.y * Byv;
    double Yi = Zk.x * Ayv + Zk.y * Axv + Zm.x * Byv - Zm.y * Bxv;
    if (i == 0 && l == 0) Yi = 0.0;   // k==0: exactly-real bin, imag = +0
    float yr = (float)Yr;
    float yi = (float)Yi;
    float mag = sqrtf(yr * yr + yi * yi);
    float ph = atan2f(sgn * yi, sgn * yr);
    out[f * HALF_N + k] = mag;
    out[MAG_SZ + f * HALF_N + k] = ph;
  }

  // ---- k = 512: Y = z[0].x - z[0].y (exactly real), (-1)^512 = +1 ----
  if (l == 0) {
    double2 z0 = z[0];
    double Yr = z0.x - z0.y;
    float yr = (float)Yr;
    out[f * HALF_N + 512] = fabsf(yr);
    out[MAG_SZ + f * HALF_N + 512] =
        __builtin_signbitf(yr) ? 3.14159265358979323846f : 0.0f;
  }
}

extern "C" void kernel_launch(void* const* d_in, const int* in_sizes, int n_in,
                              void* d_out, int out_size, void* d_ws, size_t ws_size,
                              hipStream_t stream) {
  const float* x = (const float*)d_in[0];
  float* out = (float*)d_out;
  double* ws = (double*)d_ws;

  hipLaunchKernelGGL(init_tables, dim3(4), dim3(256), 0, stream, ws);
  hipLaunchKernelGGL(zero_tail, dim3(7), dim3(256), 0, stream, out);
  hipLaunchKernelGGL(stft_frame, dim3((N_FRAMES + 3) / 4), dim3(256), 0, stream,
                     x, ws, out);
}

// Round 5
// 400.058 us; speedup vs baseline: 1.5327x; 1.0087x over previous
//
#include <hip/hip_runtime.h>

// STFT: N_FFT=1024, HOP=256, WIN=1024, SIG_LEN=2^24, pad=768 each side.
// n_frames=65539 computed frames, n_rows=65542 output rows, half_n=513.
// Circular shift by 512 (zero-phase) == multiply spectrum by (-1)^k.
//
// FP64 FFT, FP32 TRANSCENDENTALS: sign(Yi) at deep spectral nulls must
// match the fp64 reference -> FFT + untwiddle in fp64; final sqrt/atan2
// in fp32 after casting (sign-preserving).
//
// ROUND-5 (round-4 redo; __sqrtf is not a HIP builtin -> use
// __builtin_amdgcn_sqrtf): occupancy + epilogue trim.
//  - 2 waves/block (128 thr), 16 KB LDS -> 10 blocks/CU target (round-3's
//    4x32KB stuck at ~4 blocks/CU, 42% occupancy, latency-bound).
//  - Paired epilogue: A_{512-k}=conj(A_k), B_{512-k}=conj(B_k) =>
//    Y_{512-k} = conj(conj(Zm)A_k + Zk B_k). Bins k and 512-k computed
//    together: halves epilogue LDS reads (16->8 b128) and AB loads.
//  - fast_atan2f: rcp + degree-11 minimax poly (~22 insts vs ~45 libm,
//    max err ~1e-5 rad, identical branch-cut side = sign(y)).

#define SIG_LEN   16777216
#define N_FRAMES  65539
#define N_ROWS    65542
#define HALF_N    513
#define FRAMES_FLOATS (N_FRAMES * HALF_N)   // 33621507
#define MAG_SZ        (N_ROWS   * HALF_N)   // 33623046

// d_ws layout (doubles):
//   [0, 1024)        window (hamming/32), fp64
//   [1024, 1920)     tw1: 448 x double2, tw1[l*7+r-1] = e^{-2*pi*i*l*r/512}
//   [1920, 2032)     tw2: 56 x double2,  tw2[q*7+r-1] = e^{-2*pi*i*8*q*r/512}
//   [2048, 4100)     AB: 513 x {A.x,A.y,B.x,B.y}, w=e^{-i*pi*k/512},
//                    A=0.5(1-i*w), B=0.5(1+i*w)

__global__ void init_tables(double* __restrict__ ws) {
  int i = blockIdx.x * 256 + threadIdx.x;
  const double PI = 3.14159265358979323846;
  if (i < 1024) {
    ws[i] = (0.54 - 0.46 * cos(2.0 * PI * (double)i / 1023.0)) / 32.0;
  }
  if (i < 448) {
    int l = i / 7, r = i % 7 + 1;
    double a = -2.0 * PI * (double)(l * r) / 512.0;
    ws[1024 + 2 * i]     = cos(a);
    ws[1024 + 2 * i + 1] = sin(a);
  }
  if (i < 56) {
    int q = i / 7, r = i % 7 + 1;
    double a = -2.0 * PI * (double)(8 * q * r) / 512.0;
    ws[1920 + 2 * i]     = cos(a);
    ws[1920 + 2 * i + 1] = sin(a);
  }
  if (i < 513) {
    double th = PI * (double)i / 512.0;
    double c = cos(th), s = sin(th);
    ws[2048 + 4 * i]     = 0.5 * (1.0 - s);   // A.x
    ws[2048 + 4 * i + 1] = -0.5 * c;          // A.y
    ws[2048 + 4 * i + 2] = 0.5 * (1.0 + s);   // B.x
    ws[2048 + 4 * i + 3] = 0.5 * c;           // B.y
  }
}

// rows n_frames..n_rows-1 stay zero in the reference; d_out is poisoned, so write them.
__global__ void zero_tail(float* __restrict__ out) {
  int i = blockIdx.x * 256 + threadIdx.x;
  if (i < (MAG_SZ - FRAMES_FLOATS)) {   // 1539 per output
    out[FRAMES_FLOATS + i] = 0.0f;
    out[MAG_SZ + FRAMES_FLOATS + i] = 0.0f;
  }
}

#define CMUL(vr, vi, wx, wy) { double _t = (vr)*(wx) - (vi)*(wy); \
                               (vi) = (vr)*(wy) + (vi)*(wx); (vr) = _t; }

// In-place 8-point DFT, natural order in and out. y[k] = sum_n a[n] W8^{nk}.
__device__ __forceinline__ void dft8(double* ar, double* ai) {
  const double S = 0.70710678118654752440;  // sqrt(2)/2
  double s0r = ar[0] + ar[4], s0i = ai[0] + ai[4];
  double s1r = ar[0] - ar[4], s1i = ai[0] - ai[4];
  double s2r = ar[2] + ar[6], s2i = ai[2] + ai[6];
  double s3r = ar[2] - ar[6], s3i = ai[2] - ai[6];
  double t0r = ar[1] + ar[5], t0i = ai[1] + ai[5];
  double t1r = ar[1] - ar[5], t1i = ai[1] - ai[5];
  double t2r = ar[3] + ar[7], t2i = ai[3] + ai[7];
  double t3r = ar[3] - ar[7], t3i = ai[3] - ai[7];

  double e0r = s0r + s2r, e0i = s0i + s2i;
  double e2r = s0r - s2r, e2i = s0i - s2i;
  double e1r = s1r + s3i, e1i = s1i - s3r;   // s1 - i*s3
  double e3r = s1r - s3i, e3i = s1i + s3r;   // s1 + i*s3
  double o0r = t0r + t2r, o0i = t0i + t2i;
  double o2r = t0r - t2r, o2i = t0i - t2i;
  double o1r = t1r + t3i, o1i = t1i - t3r;
  double o3r = t1r - t3i, o3i = t1i + t3r;

  double u1r = S * (o1r + o1i), u1i = S * (o1i - o1r);   // W8^1 * o1
  double u2r = o2i,             u2i = -o2r;              // -i   * o2
  double u3r = S * (o3i - o3r), u3i = -S * (o3r + o3i);  // W8^3 * o3

  ar[0] = e0r + o0r; ai[0] = e0i + o0i;
  ar[4] = e0r - o0r; ai[4] = e0i - o0i;
  ar[1] = e1r + u1r; ai[1] = e1i + u1i;
  ar[5] = e1r - u1r; ai[5] = e1i - u1i;
  ar[2] = e2r + u2r; ai[2] = e2i + u2i;
  ar[6] = e2r - u2r; ai[6] = e2i - u2i;
  ar[3] = e3r + u3r; ai[3] = e3i + u3i;
  ar[7] = e3r - u3r; ai[7] = e3i - u3i;
}

// atan2 via min/max ratio + degree-11 minimax poly on [0,1].
// Max abs error ~1e-5 rad; branch-cut side decided by sign(y) exactly as
// libm (copysign), so +/-pi cuts at nulls are identical.
__device__ __forceinline__ float fast_atan2f(float y, float x) {
  const float PI   = 3.14159265358979f;
  const float PI_2 = 1.57079632679490f;
  float ax = fabsf(x), ay = fabsf(y);
  float mx = fmaxf(ax, ay), mn = fminf(ax, ay);
  float t = mn * __builtin_amdgcn_rcpf(mx);
  t = (mx == 0.0f) ? 0.0f : t;          // atan2(0,0) -> 0
  float zz = t * t;
  float a = fmaf(zz, -0.01172120f, 0.05265332f);
  a = fmaf(zz, a, -0.11643287f);
  a = fmaf(zz, a,  0.19354346f);
  a = fmaf(zz, a, -0.33262347f);
  a = fmaf(zz, a,  0.99997726f);
  a = a * t;                            // atan(mn/mx) in [0, pi/4]
  a = (ay > ax) ? (PI_2 - a) : a;
  a = (x < 0.0f) ? (PI - a) : a;
  return copysignf(a, y);
}

__global__ __launch_bounds__(128, 5) void stft_frame(const float* __restrict__ x,
                                                     const double* __restrict__ ws,
                                                     float* __restrict__ out) {
  __shared__ double2 zbuf[2][512];   // 16 KB -> 10 blocks/CU

  const int wv = threadIdx.x >> 6;   // wave id = which frame in this block
  const int l  = threadIdx.x & 63;   // lane
  const int f  = blockIdx.x * 2 + wv;
  if (f >= N_FRAMES) return;         // safe: no barriers anywhere below
  double2* z = zbuf[wv];

  const int g = l >> 3;   // high octal digit of lane
  const int q = l & 7;    // low octal digit of lane

  // ---- load + window + half-size pack: reg[n2] = z_in[64*n2 + l] ----
  double ar[8], ai[8];
  const int base = f * 256 - 768;
  if (base >= 0 && base + 1024 <= SIG_LEN) {
    // fast path: 65533 of 65539 frames
#pragma unroll
    for (int n2 = 0; n2 < 8; ++n2) {
      int j = 128 * n2 + 2 * l;
      float2 xv = *(const float2*)(x + base + j);
      double2 wn = *(const double2*)(ws + j);
      ar[n2] = (double)xv.x * wn.x;
      ai[n2] = (double)xv.y * wn.y;
    }
  } else {
#pragma unroll
    for (int n2 = 0; n2 < 8; ++n2) {
      int j  = 128 * n2 + 2 * l;
      int ix = base + j;
      double v0 = (ix >= 0 && ix < SIG_LEN) ? (double)x[ix] : 0.0;
      double v1 = (ix + 1 >= 0 && ix + 1 < SIG_LEN) ? (double)x[ix + 1] : 0.0;
      double2 wn = *(const double2*)(ws + j);
      ar[n2] = v0 * wn.x;
      ai[n2] = v1 * wn.y;
    }
  }

  // ---- stage 1: DFT over n2 (reg axis) -> k0; twiddle W512^{l*k0} ----
  dft8(ar, ai);
  {
    const double2* tw1 = (const double2*)(ws + 1024) + l * 7;
#pragma unroll
    for (int r = 1; r < 8; ++r) {
      double2 w = tw1[r - 1];
      CMUL(ar[r], ai[r], w.x, w.y);
    }
  }

  // ---- exchange A: idx_A(k0,n1,n0) = 64*k0 + 8*n1 + (n0^n1) ----
#pragma unroll
  for (int r = 0; r < 8; ++r) {
    z[64 * r + 8 * g + (q ^ g)] = make_double2(ar[r], ai[r]);
  }
  asm volatile("s_waitcnt lgkmcnt(0)" ::: "memory");
#pragma unroll
  for (int r = 0; r < 8; ++r) {
    double2 v = z[64 * g + 8 * r + (q ^ r)];
    ar[r] = v.x; ai[r] = v.y;
  }

  // ---- stage 2: DFT over n1 -> k1; twiddle W64^{n0*k1}, n0=q ----
  dft8(ar, ai);
  {
    const double2* tw2 = (const double2*)(ws + 1920) + q * 7;
#pragma unroll
    for (int r = 1; r < 8; ++r) {
      double2 w = tw2[r - 1];
      CMUL(ar[r], ai[r], w.x, w.y);
    }
  }

  // ---- exchange B: idx_B(k0,k1,n0) = 64*k0 + 8*k1 + (n0^k1) ----
  // (DS ops are in-order per wave: writes cannot pass the prior reads)
#pragma unroll
  for (int r = 0; r < 8; ++r) {
    z[64 * g + 8 * r + (q ^ r)] = make_double2(ar[r], ai[r]);
  }
  asm volatile("s_waitcnt lgkmcnt(0)" ::: "memory");
#pragma unroll
  for (int r = 0; r < 8; ++r) {
    double2 v = z[64 * g + 8 * q + (r ^ q)];
    ar[r] = v.x; ai[r] = v.y;
  }

  // ---- stage 3: DFT over n0 -> k2 (no twiddle) ----
  dft8(ar, ai);

  // ---- store: reg k2 holds X[k], k = 64*k2 + 8*q + g ----
  // idx_C(k) = (k & ~7) | ((k ^ (k>>3)) & 7)
#pragma unroll
  for (int r = 0; r < 8; ++r) {
    z[64 * r + 8 * q + (g ^ q)] = make_double2(ar[r], ai[r]);
  }
  asm volatile("s_waitcnt lgkmcnt(0)" ::: "memory");

  // ---- paired untwiddle: bins k (0..255) and 512-k (257..512) ----
  // Y_k      = Zk*A + conj(Zm)*B
  // Y_{512-k}= conj(conj(Zm)*A + Zk*B)    (A,B tables satisfy the conj pair)
  const double* AB = ws + 2048;
  const int czk = 8 * g + (q ^ g);         // idx_C(64*i + l) - 64*i
  const float sgn = (l & 1) ? -1.0f : 1.0f;  // (-1)^k; parity(512-k)==parity(k)
  float* outm = out + f * HALF_N;
  float* outp = out + MAG_SZ + f * HALF_N;
#pragma unroll
  for (int i = 0; i < 4; ++i) {
    int k  = 64 * i + l;                   // 0..255
    int km = 512 - k;                      // 257..512 (k=0 -> 512)
    double2 Zk = z[64 * i + czk];
    int zmi = km & 511;
    zmi = (zmi & ~7) | ((zmi ^ (zmi >> 3)) & 7);
    double2 Zm = z[zmi];
    const double* ab = AB + 4 * k;
    double Axv = ab[0], Ayv = ab[1], Bxv = ab[2], Byv = ab[3];
    double Yr  = Zk.x * Axv - Zk.y * Ayv + Zm.x * Bxv + Zm.y * Byv;
    double Yi  = Zk.x * Ayv + Zk.y * Axv + Zm.x * Byv - Zm.y * Bxv;
    double Y2r = Zm.x * Axv + Zm.y * Ayv + Zk.x * Bxv - Zk.y * Byv;
    double Y2i = -(Zm.x * Ayv - Zm.y * Axv + Zk.x * Byv + Zk.y * Bxv);
    if (i == 0) {
      if (l == 0) { Yi = 0.0; Y2i = 0.0; }  // bins 0 and 512: exactly real
    }
    float yr  = (float)Yr,  yi  = (float)Yi;
    float y2r = (float)Y2r, y2i = (float)Y2i;
    float mag1 = __builtin_amdgcn_sqrtf(fmaf(yr, yr, yi * yi));
    float ph1  = fast_atan2f(sgn * yi, sgn * yr);
    float mag2 = __builtin_amdgcn_sqrtf(fmaf(y2r, y2r, y2i * y2i));
    float ph2  = fast_atan2f(sgn * y2i, sgn * y2r);
    outm[k]  = mag1;
    outp[k]  = ph1;
    outm[km] = mag2;
    outp[km] = ph2;
  }

  // ---- bin 256: A=0, B=1 exactly -> Y = conj(z[256]); idx_C(256)=256 ----
  if (l == 0) {
    double2 zc = z[256];
    float yr = (float)zc.x, yi = (float)(-zc.y);
    outm[256] = __builtin_amdgcn_sqrtf(fmaf(yr, yr, yi * yi));
    outp[256] = fast_atan2f(yi, yr);       // (-1)^256 = +1
  }
}

extern "C" void kernel_launch(void* const* d_in, const int* in_sizes, int n_in,
                              void* d_out, int out_size, void* d_ws, size_t ws_size,
                              hipStream_t stream) {
  const float* x = (const float*)d_in[0];
  float* out = (float*)d_out;
  double* ws = (double*)d_ws;

  hipLaunchKernelGGL(init_tables, dim3(4), dim3(256), 0, stream, ws);
  hipLaunchKernelGGL(zero_tail, dim3(7), dim3(256), 0, stream, out);
  hipLaunchKernelGGL(stft_frame, dim3((N_FRAMES + 1) / 2), dim3(128), 0, stream,
                     x, ws, out);
}